// Round 1
// baseline (864.711 us; speedup 1.0000x reference)
//
#include <hip/hip_runtime.h>
#include <cstdint>

typedef __bf16 bf16_t;
typedef bf16_t bf16x8 __attribute__((ext_vector_type(8)));
typedef bf16_t bf16x4 __attribute__((ext_vector_type(4)));
typedef float  floatx4 __attribute__((ext_vector_type(4)));

#define S_ALL 2304
#define SIMG  2048
#define NH    24
#define HD    128
#define DIM   3072
#define NQKV  9216

typedef __attribute__((address_space(1))) void* gp1_t;
typedef __attribute__((address_space(3))) void* lp3_t;

__device__ __forceinline__ void async16(const void* g, void* l) {
    __builtin_amdgcn_global_load_lds((gp1_t)(g), (lp3_t)(l), 16, 0, 0);
}
__device__ __forceinline__ floatx4 mfma_bf16(bf16x8 a, bf16x8 b, floatx4 c) {
    return __builtin_amdgcn_mfma_f32_16x16x32_bf16(a, b, c, 0, 0, 0);
}

// ---------------- x concat + fp32->bf16 ----------------
__global__ __launch_bounds__(256) void k_convert_x(const float* __restrict__ hid,
                                                   const float* __restrict__ enc,
                                                   bf16_t* __restrict__ xb) {
    long i = ((long)blockIdx.x * 256 + threadIdx.x) * 4;
    const long HN = (long)SIMG * DIM;
    float4 f = (i < HN) ? *(const float4*)(hid + i) : *(const float4*)(enc + (i - HN));
    bf16x4 o;
    o[0] = (bf16_t)f.x; o[1] = (bf16_t)f.y; o[2] = (bf16_t)f.z; o[3] = (bf16_t)f.w;
    *(bf16x4*)(xb + i) = o;
}

// ---------------- weight transpose-convert: W fp32 [3072][3072] -> Wt bf16 [n][k] ----------------
__global__ __launch_bounds__(256) void k_wT(const float* __restrict__ W, bf16_t* __restrict__ Wt) {
    __shared__ __align__(16) bf16_t T[64][72];
    int r0 = blockIdx.x * 64, c0 = blockIdx.y * 64;
    int tid = threadIdx.x;
    int lr = tid >> 2, lc = (tid & 3) * 16;
    const float* src = W + (long)(r0 + lr) * DIM + c0 + lc;
#pragma unroll
    for (int i = 0; i < 16; i += 4) {
        float4 f = *(const float4*)(src + i);
        T[lr][lc + i + 0] = (bf16_t)f.x;
        T[lr][lc + i + 1] = (bf16_t)f.y;
        T[lr][lc + i + 2] = (bf16_t)f.z;
        T[lr][lc + i + 3] = (bf16_t)f.w;
    }
    __syncthreads();
    bf16x8 a, b;
#pragma unroll
    for (int i = 0; i < 8; i++) a[i] = T[lc + i][lr];
#pragma unroll
    for (int i = 0; i < 8; i++) b[i] = T[lc + 8 + i][lr];
    bf16_t* dst = Wt + (long)(c0 + lr) * DIM + r0 + lc;
    *(bf16x8*)dst = a;
    *(bf16x8*)(dst + 8) = b;
}

// ---------------- bias concat ----------------
__global__ __launch_bounds__(256) void k_bias(const float* __restrict__ bq, const float* __restrict__ bk,
                                              const float* __restrict__ bv, float* __restrict__ bcat) {
    int i = blockIdx.x * 256 + threadIdx.x;
    float v = (i < DIM) ? bq[i] : (i < 2 * DIM ? bk[i - DIM] : bv[i - 2 * DIM]);
    bcat[i] = v;
}

// ---------------- GEMM: C[M,N] = A[M,K] * Bt[N,K]^T + bias ----------------
// 128x128 tile, 4 waves in 2x2, 16x16x32 bf16 MFMA, global_load_lds width-16 staging.
__global__ __launch_bounds__(256) void k_gemm_bt(const bf16_t* __restrict__ A,
                                                 const bf16_t* __restrict__ Bt,
                                                 const float* __restrict__ bias,
                                                 bf16_t* __restrict__ Cb, float* __restrict__ Cf,
                                                 int M, int N, int K) {
    __shared__ __align__(16) bf16_t As[128 * 64];
    __shared__ __align__(16) bf16_t Bs[128 * 64];
    int tid = threadIdx.x;
    int wave = tid >> 6, lane = tid & 63;
    int quad = lane >> 4, l16 = lane & 15;
    long m0 = (long)blockIdx.y * 128, n0 = (long)blockIdx.x * 128;
    int wm = (wave >> 1) * 64, wn = (wave & 1) * 64;

    floatx4 zero = {0.f, 0.f, 0.f, 0.f};
    floatx4 acc[4][4];
#pragma unroll
    for (int i = 0; i < 4; i++)
#pragma unroll
        for (int j = 0; j < 4; j++) acc[i][j] = zero;

    const bf16_t* Ag = A + (m0 + wave * 32 + (lane >> 3)) * K + (lane & 7) * 8;
    const bf16_t* Bg = Bt + (n0 + wave * 32 + (lane >> 3)) * K + (lane & 7) * 8;
    char* AsB = (char*)As + wave * 4096;
    char* BsB = (char*)Bs + wave * 4096;

    for (int k0 = 0; k0 < K; k0 += 64) {
#pragma unroll
        for (int c2 = 0; c2 < 4; ++c2) {
            async16(Ag + (long)c2 * 8 * K + k0, AsB + c2 * 1024);
            async16(Bg + (long)c2 * 8 * K + k0, BsB + c2 * 1024);
        }
        __syncthreads();
#pragma unroll
        for (int ks = 0; ks < 2; ++ks) {
            bf16x8 af[4], bfr[4];
#pragma unroll
            for (int i = 0; i < 4; i++)
                af[i] = *(const bf16x8*)&As[(wm + i * 16 + l16) * 64 + ks * 32 + quad * 8];
#pragma unroll
            for (int i = 0; i < 4; i++)
                bfr[i] = *(const bf16x8*)&Bs[(wn + i * 16 + l16) * 64 + ks * 32 + quad * 8];
#pragma unroll
            for (int i = 0; i < 4; i++)
#pragma unroll
                for (int j = 0; j < 4; j++) acc[i][j] = mfma_bf16(af[i], bfr[j], acc[i][j]);
        }
        __syncthreads();
    }

#pragma unroll
    for (int i = 0; i < 4; i++) {
        long rowb = m0 + wm + i * 16 + quad * 4;
#pragma unroll
        for (int j = 0; j < 4; j++) {
            long col = n0 + wn + j * 16 + l16;
            float bv = bias ? bias[col] : 0.0f;
#pragma unroll
            for (int r = 0; r < 4; r++) {
                float v = acc[i][j][r] + bv;
                long idx = (rowb + r) * N + col;
                if (Cb) Cb[idx] = (bf16_t)v;
                else    Cf[idx] = v;
            }
        }
    }
}

// ---------------- q/k epilogue: bias already added; RMSNorm + RoPE + (q) score scale ----------------
// one wave per (tensor t in {q,k}, head h, seq s); lane owns dims {2*lane, 2*lane+1}
__global__ __launch_bounds__(256) void k_qk_epi(const bf16_t* __restrict__ qkvb,
                                                const float* __restrict__ rope_cos,
                                                const float* __restrict__ rope_sin,
                                                const float* __restrict__ nqw,
                                                const float* __restrict__ nkw,
                                                bf16_t* __restrict__ qo, bf16_t* __restrict__ ko) {
    int tid = threadIdx.x, wave = tid >> 6, lane = tid & 63;
    int row_id = blockIdx.x * 4 + wave;  // 0 .. 110591
    int t = row_id / (S_ALL * NH);
    int rem = row_id - t * (S_ALL * NH);
    int h = rem / S_ALL;
    int s = rem - h * S_ALL;
    const bf16_t* src = qkvb + (long)s * NQKV + t * DIM + h * HD + lane * 2;
    float x0 = (float)src[0], x1 = (float)src[1];
    float ss = x0 * x0 + x1 * x1;
#pragma unroll
    for (int off = 1; off < 64; off <<= 1) ss += __shfl_xor(ss, off);
    float r = rsqrtf(ss * (1.0f / 128.0f) + 1e-6f);
    const float* w = t ? nkw : nqw;
    x0 *= r * w[lane * 2];
    x1 *= r * w[lane * 2 + 1];
    if (s < SIMG) {
        float c = rope_cos[s * HD + lane * 2];
        float sn = rope_sin[s * HD + lane * 2];
        float y0 = x0 * c - x1 * sn;
        float y1 = x1 * c + x0 * sn;
        x0 = y0; x1 = y1;
    }
    if (t == 0) { x0 *= 0.08838834764831845f; x1 *= 0.08838834764831845f; }
    bf16_t* dst = (t ? ko : qo) + (long)h * S_ALL * HD + (long)s * HD + lane * 2;
    dst[0] = (bf16_t)x0;
    dst[1] = (bf16_t)x1;
}

// ---------------- V transpose: qkvb v-part [s][d] per head -> vT [h][d][s] ----------------
__global__ __launch_bounds__(256) void k_vT(const bf16_t* __restrict__ qkvb, bf16_t* __restrict__ vT) {
    __shared__ __align__(16) bf16_t T[64][72];
    int h = blockIdx.z;
    int s0 = blockIdx.x * 64, d0 = blockIdx.y * 64;
    int tid = threadIdx.x, lr = tid >> 2, lc = (tid & 3) * 16;
    const bf16_t* src = qkvb + (long)(s0 + lr) * NQKV + 2 * DIM + h * HD + d0 + lc;
    bf16x8 a = *(const bf16x8*)src, b = *(const bf16x8*)(src + 8);
#pragma unroll
    for (int i = 0; i < 8; i++) { T[lr][lc + i] = a[i]; T[lr][lc + 8 + i] = b[i]; }
    __syncthreads();
    bf16x8 c, d;
#pragma unroll
    for (int i = 0; i < 8; i++) c[i] = T[lc + i][lr];
#pragma unroll
    for (int i = 0; i < 8; i++) d[i] = T[lc + 8 + i][lr];
    bf16_t* dst = vT + (long)h * HD * S_ALL + (long)(d0 + lr) * S_ALL + s0 + lc;
    *(bf16x8*)dst = c;
    *(bf16x8*)(dst + 8) = d;
}

// ---------------- flash attention ----------------
// grid (36, 24): 64 q-rows per block, 4 waves x 16 q-rows; K-blocks of 64.
__global__ __launch_bounds__(256) void k_attn(const bf16_t* __restrict__ q,
                                              const bf16_t* __restrict__ k,
                                              const bf16_t* __restrict__ vT,
                                              bf16_t* __restrict__ ao,
                                              float* __restrict__ out_txt) {
    __shared__ __align__(16) bf16_t Ks[64 * 128];   // [key][dim]
    __shared__ __align__(16) bf16_t VTs[128 * 64];  // [dim][key]
    __shared__ __align__(16) bf16_t Ps[4][16 * 64]; // per-wave [qrow][key]
    int tid = threadIdx.x, wave = tid >> 6, lane = tid & 63;
    int quad = lane >> 4, l16 = lane & 15;
    int h = blockIdx.y;
    int q0 = blockIdx.x * 64 + wave * 16;
    const long hbase = (long)h * S_ALL * HD;

    bf16x8 qf[4];
    {
        const bf16_t* qp = q + hbase + (long)(q0 + l16) * HD + quad * 8;
#pragma unroll
        for (int ks = 0; ks < 4; ++ks) qf[ks] = *(const bf16x8*)(qp + ks * 32);
    }
    float m_i[4], l_i[4];
#pragma unroll
    for (int j = 0; j < 4; j++) { m_i[j] = -1e30f; l_i[j] = 0.f; }
    floatx4 zero = {0.f, 0.f, 0.f, 0.f};
    floatx4 o[8];
#pragma unroll
    for (int ni = 0; ni < 8; ni++) o[ni] = zero;

    const bf16_t* kgb = k + hbase;
    const bf16_t* vgb = vT + hbase;

    for (int kb = 0; kb < S_ALL / 64; ++kb) {
        const bf16_t* kg = kgb + (long)kb * 64 * HD;
        const bf16_t* vg = vgb + kb * 64;
#pragma unroll
        for (int c2 = 0; c2 < 4; ++c2) {
            int c = wave * 4 + c2;
            async16(kg + (long)(c * 4 + quad) * HD + l16 * 8, (char*)Ks + c * 1024);
            async16(vg + (long)(c * 8 + (lane >> 3)) * S_ALL + (lane & 7) * 8, (char*)VTs + c * 1024);
        }
        __syncthreads();

        // S = Q K^T  (q pre-scaled by 1/sqrt(128))
        floatx4 s[4];
#pragma unroll
        for (int ni = 0; ni < 4; ni++) s[ni] = zero;
#pragma unroll
        for (int ni = 0; ni < 4; ++ni)
#pragma unroll
            for (int ks = 0; ks < 4; ++ks) {
                bf16x8 bfr = *(const bf16x8*)&Ks[(ni * 16 + l16) * HD + ks * 32 + quad * 8];
                s[ni] = mfma_bf16(qf[ks], bfr, s[ni]);
            }

        // online softmax (rows quad*4+j live in this quad's 16 lanes)
        float alpha[4];
#pragma unroll
        for (int j = 0; j < 4; j++) {
            float mx = fmaxf(fmaxf(s[0][j], s[1][j]), fmaxf(s[2][j], s[3][j]));
#pragma unroll
            for (int off = 1; off < 16; off <<= 1) mx = fmaxf(mx, __shfl_xor(mx, off));
            float mnew = fmaxf(m_i[j], mx);
            float a = __expf(m_i[j] - mnew);
            m_i[j] = mnew;
            float rs = 0.f;
#pragma unroll
            for (int ni = 0; ni < 4; ++ni) {
                float p = __expf(s[ni][j] - mnew);
                s[ni][j] = p;
                rs += p;
            }
#pragma unroll
            for (int off = 1; off < 16; off <<= 1) rs += __shfl_xor(rs, off);
            l_i[j] = l_i[j] * a + rs;
            alpha[j] = a;
        }
#pragma unroll
        for (int ni = 0; ni < 8; ++ni)
#pragma unroll
            for (int j = 0; j < 4; j++) o[ni][j] *= alpha[j];

        // P -> own LDS region (C-layout -> A-layout round trip)
#pragma unroll
        for (int ni = 0; ni < 4; ++ni)
#pragma unroll
            for (int j = 0; j < 4; j++)
                Ps[wave][(quad * 4 + j) * 64 + ni * 16 + l16] = (bf16_t)s[ni][j];

        // O += P V
        bf16x8 pf[2];
#pragma unroll
        for (int ks = 0; ks < 2; ++ks)
            pf[ks] = *(const bf16x8*)&Ps[wave][l16 * 64 + ks * 32 + quad * 8];
#pragma unroll
        for (int ni = 0; ni < 8; ++ni)
#pragma unroll
            for (int ks = 0; ks < 2; ++ks) {
                bf16x8 bfr = *(const bf16x8*)&VTs[(ni * 16 + l16) * 64 + ks * 32 + quad * 8];
                o[ni] = mfma_bf16(pf[ks], bfr, o[ni]);
            }
        __syncthreads();
    }

#pragma unroll
    for (int j = 0; j < 4; j++) {
        float rl = 1.0f / l_i[j];
        int s_row = q0 + quad * 4 + j;
#pragma unroll
        for (int ni = 0; ni < 8; ++ni) {
            float v = o[ni][j] * rl;
            int col = h * HD + ni * 16 + l16;
            ao[(long)s_row * DIM + col] = (bf16_t)v;
            if (s_row >= SIMG) out_txt[(long)(s_row - SIMG) * DIM + col] = v;
        }
    }
}

// ---------------- launch ----------------
extern "C" void kernel_launch(void* const* d_in, const int* in_sizes, int n_in,
                              void* d_out, int out_size, void* d_ws, size_t ws_size,
                              hipStream_t stream) {
    const float* hid = (const float*)d_in[0];
    const float* enc = (const float*)d_in[1];
    const float* rope_cos = (const float*)d_in[2];
    const float* rope_sin = (const float*)d_in[3];
    const float* wq = (const float*)d_in[4];
    const float* bq = (const float*)d_in[5];
    const float* wk = (const float*)d_in[6];
    const float* bk = (const float*)d_in[7];
    const float* wv = (const float*)d_in[8];
    const float* bv = (const float*)d_in[9];
    const float* nqw = (const float*)d_in[10];
    const float* nkw = (const float*)d_in[11];
    const float* wo = (const float*)d_in[12];
    const float* bo = (const float*)d_in[13];
    float* out = (float*)d_out;

    char* ws = (char*)d_ws;
    bf16_t* xb   = (bf16_t*)(ws);                 // 2304*3072 bf16      = 14,155,776 B
    bf16_t* wTq  = (bf16_t*)(ws + 14155776L);     // 3*3072*3072 bf16    = 56,623,104 B
    bf16_t* woT  = (bf16_t*)(ws + 70778880L);     // 3072*3072 bf16      = 18,874,368 B
    float*  bcat = (float*) (ws + 89653248L);     // 9216 f32            = 36,864 B
    bf16_t* qkvb = (bf16_t*)(ws + 89690112L);     // 2304*9216 bf16      = 42,467,328 B
    bf16_t* qb   = (bf16_t*)(ws + 132157440L);    // 24*2304*128 bf16    = 14,155,776 B
    bf16_t* kbuf = (bf16_t*)(ws + 146313216L);    // same
    bf16_t* vT   = (bf16_t*)(ws + 160468992L);    // same
    bf16_t* ao   = (bf16_t*)(ws + 174624768L);    // 2304*3072 bf16

    k_convert_x<<<6912, 256, 0, stream>>>(hid, enc, xb);
    dim3 tg(48, 48);
    k_wT<<<tg, 256, 0, stream>>>(wq, wTq);
    k_wT<<<tg, 256, 0, stream>>>(wk, wTq + 3072L * 3072);
    k_wT<<<tg, 256, 0, stream>>>(wv, wTq + 2 * 3072L * 3072);
    k_wT<<<tg, 256, 0, stream>>>(wo, woT);
    k_bias<<<36, 256, 0, stream>>>(bq, bk, bv, bcat);
    k_gemm_bt<<<dim3(72, 18), 256, 0, stream>>>(xb, wTq, bcat, qkvb, (float*)nullptr, S_ALL, NQKV, DIM);
    k_qk_epi<<<27648, 256, 0, stream>>>(qkvb, rope_cos, rope_sin, nqw, nkw, qb, kbuf);
    k_vT<<<dim3(36, 2, 24), 256, 0, stream>>>(qkvb, vT);
    k_attn<<<dim3(36, 24), 256, 0, stream>>>(qb, kbuf, vT, ao, out + (long)SIMG * DIM);
    k_gemm_bt<<<dim3(24, 16), 256, 0, stream>>>(ao, woT, bo, (bf16_t*)nullptr, out, SIMG, DIM, DIM);
}

// Round 2
// 645.260 us; speedup vs baseline: 1.3401x; 1.3401x over previous
//
#include <hip/hip_runtime.h>
#include <cstdint>

typedef __bf16 bf16_t;
typedef bf16_t bf16x8 __attribute__((ext_vector_type(8)));
typedef bf16_t bf16x4 __attribute__((ext_vector_type(4)));
typedef float  floatx4 __attribute__((ext_vector_type(4)));

#define S_ALL 2304
#define SIMG  2048
#define NH    24
#define HD    128
#define DIM   3072
#define NQKV  9216

// exp(s-12) computed as exp2(s*log2e - 12*log2e); log2e folded into q pre-scale
#define SHIFT2 17.312340490667562f
#define QSCALE 0.12751744f   /* (1/sqrt(128)) * log2(e) */

typedef __attribute__((address_space(1))) void* gp1_t;
typedef __attribute__((address_space(3))) void* lp3_t;

__device__ __forceinline__ void async16(const void* g, void* l) {
    __builtin_amdgcn_global_load_lds((gp1_t)(g), (lp3_t)(l), 16, 0, 0);
}
__device__ __forceinline__ floatx4 mfma_bf16(bf16x8 a, bf16x8 b, floatx4 c) {
    return __builtin_amdgcn_mfma_f32_16x16x32_bf16(a, b, c, 0, 0, 0);
}

// ---------------- x concat + fp32->bf16 ----------------
__global__ __launch_bounds__(256) void k_convert_x(const float* __restrict__ hid,
                                                   const float* __restrict__ enc,
                                                   bf16_t* __restrict__ xb) {
    long i = ((long)blockIdx.x * 256 + threadIdx.x) * 4;
    const long HN = (long)SIMG * DIM;
    float4 f = (i < HN) ? *(const float4*)(hid + i) : *(const float4*)(enc + (i - HN));
    bf16x4 o;
    o[0] = (bf16_t)f.x; o[1] = (bf16_t)f.y; o[2] = (bf16_t)f.z; o[3] = (bf16_t)f.w;
    *(bf16x4*)(xb + i) = o;
}

// ---------------- weight transpose-convert: W fp32 [3072][3072] -> Wt bf16 [n][k] ----------------
__global__ __launch_bounds__(256) void k_wT(const float* __restrict__ W, bf16_t* __restrict__ Wt) {
    __shared__ __align__(16) bf16_t T[64][72];
    int r0 = blockIdx.x * 64, c0 = blockIdx.y * 64;
    int tid = threadIdx.x;
    int lr = tid >> 2, lc = (tid & 3) * 16;
    const float* src = W + (long)(r0 + lr) * DIM + c0 + lc;
#pragma unroll
    for (int i = 0; i < 16; i += 4) {
        float4 f = *(const float4*)(src + i);
        T[lr][lc + i + 0] = (bf16_t)f.x;
        T[lr][lc + i + 1] = (bf16_t)f.y;
        T[lr][lc + i + 2] = (bf16_t)f.z;
        T[lr][lc + i + 3] = (bf16_t)f.w;
    }
    __syncthreads();
    bf16x8 a, b;
#pragma unroll
    for (int i = 0; i < 8; i++) a[i] = T[lc + i][lr];
#pragma unroll
    for (int i = 0; i < 8; i++) b[i] = T[lc + 8 + i][lr];
    bf16_t* dst = Wt + (long)(c0 + lr) * DIM + r0 + lc;
    *(bf16x8*)dst = a;
    *(bf16x8*)(dst + 8) = b;
}

// ---------------- bias concat ----------------
__global__ __launch_bounds__(256) void k_bias(const float* __restrict__ bq, const float* __restrict__ bk,
                                              const float* __restrict__ bv, float* __restrict__ bcat) {
    int i = blockIdx.x * 256 + threadIdx.x;
    float v = (i < DIM) ? bq[i] : (i < 2 * DIM ? bk[i - DIM] : bv[i - 2 * DIM]);
    bcat[i] = v;
}

// ---------------- GEMM: C[M,N] = A[M,K] * Bt[N,K]^T + bias ----------------
__global__ __launch_bounds__(256) void k_gemm_bt(const bf16_t* __restrict__ A,
                                                 const bf16_t* __restrict__ Bt,
                                                 const float* __restrict__ bias,
                                                 bf16_t* __restrict__ Cb, float* __restrict__ Cf,
                                                 int M, int N, int K) {
    __shared__ __align__(16) bf16_t As[128 * 64];
    __shared__ __align__(16) bf16_t Bs[128 * 64];
    int tid = threadIdx.x;
    int wave = tid >> 6, lane = tid & 63;
    int quad = lane >> 4, l16 = lane & 15;
    long m0 = (long)blockIdx.y * 128, n0 = (long)blockIdx.x * 128;
    int wm = (wave >> 1) * 64, wn = (wave & 1) * 64;

    floatx4 zero = {0.f, 0.f, 0.f, 0.f};
    floatx4 acc[4][4];
#pragma unroll
    for (int i = 0; i < 4; i++)
#pragma unroll
        for (int j = 0; j < 4; j++) acc[i][j] = zero;

    const bf16_t* Ag = A + (m0 + wave * 32 + (lane >> 3)) * K + (lane & 7) * 8;
    const bf16_t* Bg = Bt + (n0 + wave * 32 + (lane >> 3)) * K + (lane & 7) * 8;
    char* AsB = (char*)As + wave * 4096;
    char* BsB = (char*)Bs + wave * 4096;

    for (int k0 = 0; k0 < K; k0 += 64) {
#pragma unroll
        for (int c2 = 0; c2 < 4; ++c2) {
            async16(Ag + (long)c2 * 8 * K + k0, AsB + c2 * 1024);
            async16(Bg + (long)c2 * 8 * K + k0, BsB + c2 * 1024);
        }
        __syncthreads();
#pragma unroll
        for (int ks = 0; ks < 2; ++ks) {
            bf16x8 af[4], bfr[4];
#pragma unroll
            for (int i = 0; i < 4; i++)
                af[i] = *(const bf16x8*)&As[(wm + i * 16 + l16) * 64 + ks * 32 + quad * 8];
#pragma unroll
            for (int i = 0; i < 4; i++)
                bfr[i] = *(const bf16x8*)&Bs[(wn + i * 16 + l16) * 64 + ks * 32 + quad * 8];
#pragma unroll
            for (int i = 0; i < 4; i++)
#pragma unroll
                for (int j = 0; j < 4; j++) acc[i][j] = mfma_bf16(af[i], bfr[j], acc[i][j]);
        }
        __syncthreads();
    }

#pragma unroll
    for (int i = 0; i < 4; i++) {
        long rowb = m0 + wm + i * 16 + quad * 4;
#pragma unroll
        for (int j = 0; j < 4; j++) {
            long col = n0 + wn + j * 16 + l16;
            float bv = bias ? bias[col] : 0.0f;
#pragma unroll
            for (int r = 0; r < 4; r++) {
                float v = acc[i][j][r] + bv;
                long idx = (rowb + r) * N + col;
                if (Cb) Cb[idx] = (bf16_t)v;
                else    Cf[idx] = v;
            }
        }
    }
}

// ---------------- q/k epilogue: RMSNorm + RoPE + (q) scale*log2e ----------------
__global__ __launch_bounds__(256) void k_qk_epi(const bf16_t* __restrict__ qkvb,
                                                const float* __restrict__ rope_cos,
                                                const float* __restrict__ rope_sin,
                                                const float* __restrict__ nqw,
                                                const float* __restrict__ nkw,
                                                bf16_t* __restrict__ qo, bf16_t* __restrict__ ko) {
    int tid = threadIdx.x, wave = tid >> 6, lane = tid & 63;
    int row_id = blockIdx.x * 4 + wave;  // 0 .. 110591
    int t = row_id / (S_ALL * NH);
    int rem = row_id - t * (S_ALL * NH);
    int h = rem / S_ALL;
    int s = rem - h * S_ALL;
    const bf16_t* src = qkvb + (long)s * NQKV + t * DIM + h * HD + lane * 2;
    float x0 = (float)src[0], x1 = (float)src[1];
    float ss = x0 * x0 + x1 * x1;
#pragma unroll
    for (int off = 1; off < 64; off <<= 1) ss += __shfl_xor(ss, off);
    float r = rsqrtf(ss * (1.0f / 128.0f) + 1e-6f);
    const float* w = t ? nkw : nqw;
    x0 *= r * w[lane * 2];
    x1 *= r * w[lane * 2 + 1];
    if (s < SIMG) {
        float c = rope_cos[s * HD + lane * 2];
        float sn = rope_sin[s * HD + lane * 2];
        float y0 = x0 * c - x1 * sn;
        float y1 = x1 * c + x0 * sn;
        x0 = y0; x1 = y1;
    }
    if (t == 0) { x0 *= QSCALE; x1 *= QSCALE; }
    bf16_t* dst = (t ? ko : qo) + (long)h * S_ALL * HD + (long)s * HD + lane * 2;
    dst[0] = (bf16_t)x0;
    dst[1] = (bf16_t)x1;
}

// ---------------- V transpose: qkvb v-part [s][d] per head -> vT [h][d][s] ----------------
__global__ __launch_bounds__(256) void k_vT(const bf16_t* __restrict__ qkvb, bf16_t* __restrict__ vT) {
    __shared__ __align__(16) bf16_t T[64][72];
    int h = blockIdx.z;
    int s0 = blockIdx.x * 64, d0 = blockIdx.y * 64;
    int tid = threadIdx.x, lr = tid >> 2, lc = (tid & 3) * 16;
    const bf16_t* src = qkvb + (long)(s0 + lr) * NQKV + 2 * DIM + h * HD + d0 + lc;
    bf16x8 a = *(const bf16x8*)src, b = *(const bf16x8*)(src + 8);
#pragma unroll
    for (int i = 0; i < 8; i++) { T[lr][lc + i] = a[i]; T[lr][lc + 8 + i] = b[i]; }
    __syncthreads();
    bf16x8 c, d;
#pragma unroll
    for (int i = 0; i < 8; i++) c[i] = T[lc + i][lr];
#pragma unroll
    for (int i = 0; i < 8; i++) d[i] = T[lc + 8 + i][lr];
    bf16_t* dst = vT + (long)h * HD * S_ALL + (long)(d0 + lr) * S_ALL + s0 + lc;
    *(bf16x8*)dst = c;
    *(bf16x8*)(dst + 8) = d;
}

// ---------------- flash attention v2: swizzled LDS, fixed-shift softmax ----------------
// grid (18, 24): 128 q-rows/block, 4 waves x 32 q-rows (2 subtiles of 16); K-blocks of 64.
// LDS swizzles (16B chunks): Ks (16 chunks/row): slot = r*16 + (c ^ (r&15))
//                            VTs (8 chunks/row): slot = r*8 + (c ^ (r&7) ^ ((r>>3&1)<<2))
//                            Ps  (8 chunks/row): slot = r*8 + (c ^ ((r>>1)&7))
__global__ __launch_bounds__(256, 2) void k_attn(const bf16_t* __restrict__ q,
                                                 const bf16_t* __restrict__ k,
                                                 const bf16_t* __restrict__ vT,
                                                 bf16_t* __restrict__ ao,
                                                 float* __restrict__ out_txt) {
    __shared__ __align__(16) bf16_t Ks[64 * 128];       // 16 KB
    __shared__ __align__(16) bf16_t VTs[128 * 64];      // 16 KB
    __shared__ __align__(16) bf16_t Ps[4][2][16 * 64];  // 16 KB (per wave, per subtile)
    int tid = threadIdx.x, wave = tid >> 6, lane = tid & 63;
    int quad = lane >> 4, l16 = lane & 15;
    int h = blockIdx.y;
    int q0 = blockIdx.x * 128 + wave * 32;
    const long hbase = (long)h * S_ALL * HD;
    const char* kgb = (const char*)(k + hbase);
    const char* vgb = (const char*)(vT + hbase);

    // staging per-lane precompute (swizzle applied on the source side; LDS dst stays contiguous)
    int koffB[4], voffB[4], slotB[4];
#pragma unroll
    for (int c2 = 0; c2 < 4; ++c2) {
        int L = (wave * 4 + c2) * 64 + lane;
        slotB[c2] = L;
        int rk = L >> 4, ck = (L & 15) ^ (rk & 15);
        koffB[c2] = rk * 256 + ck * 16;
        int rv = L >> 3, cv = (L & 7) ^ (rv & 7) ^ (((rv >> 3) & 1) << 2);
        voffB[c2] = rv * (S_ALL * 2) + cv * 16;
    }

    // q fragments (A-layout), pre-scaled by QSCALE in k_qk_epi
    bf16x8 qf[2][4];
#pragma unroll
    for (int st = 0; st < 2; ++st) {
        const bf16_t* qp = q + hbase + (long)(q0 + st * 16 + l16) * HD + quad * 8;
#pragma unroll
        for (int ks = 0; ks < 4; ++ks) qf[st][ks] = *(const bf16x8*)(qp + ks * 32);
    }

    floatx4 zero = {0.f, 0.f, 0.f, 0.f};
    floatx4 o0[8], o1[8];
#pragma unroll
    for (int ni = 0; ni < 8; ++ni) { o0[ni] = zero; o1[ni] = zero; }
    floatx4 lac0 = zero, lac1 = zero;

    for (int kb = 0; kb < S_ALL / 64; ++kb) {
        const char* kg = kgb + (long)kb * 16384;
        const char* vg = vgb + kb * 128;
#pragma unroll
        for (int c2 = 0; c2 < 4; ++c2) {
            async16(kg + koffB[c2], (char*)Ks + slotB[c2] * 16);
            async16(vg + voffB[c2], (char*)VTs + slotB[c2] * 16);
        }
        __syncthreads();

        // S = Q K^T (both subtiles share each K fragment)
        floatx4 s0[4], s1[4];
#pragma unroll
        for (int ni = 0; ni < 4; ++ni) { s0[ni] = zero; s1[ni] = zero; }
#pragma unroll
        for (int ks = 0; ks < 4; ++ks)
#pragma unroll
            for (int ni = 0; ni < 4; ++ni) {
                int slot = (ni * 16 + l16) * 16 + ((ks * 4 + quad) ^ l16);
                bf16x8 kf = *(const bf16x8*)&Ks[slot * 8];
                s0[ni] = mfma_bf16(qf[0][ks], kf, s0[ni]);
                s1[ni] = mfma_bf16(qf[1][ks], kf, s1[ni]);
            }

        // fixed-shift softmax: p = exp2(s - 12*log2e); no max pass, no rescale
#pragma unroll
        for (int st = 0; st < 2; ++st) {
#pragma unroll
            for (int ni = 0; ni < 4; ++ni) {
                floatx4 sv = st ? s1[ni] : s0[ni];
                floatx4 p;
#pragma unroll
                for (int j = 0; j < 4; ++j) p[j] = __builtin_amdgcn_exp2f(sv[j] - SHIFT2);
                if (st) lac1 += p; else lac0 += p;
#pragma unroll
                for (int j = 0; j < 4; ++j) {
                    int r = quad * 4 + j;
                    int chunk = ((ni * 16 + l16) >> 3) ^ ((r >> 1) & 7);
                    Ps[wave][st][r * 64 + chunk * 8 + (l16 & 7)] = (bf16_t)p[j];
                }
            }
        }

        // P back as A-fragments
        bf16x8 pf[2][2];
#pragma unroll
        for (int st = 0; st < 2; ++st)
#pragma unroll
            for (int k2 = 0; k2 < 2; ++k2) {
                int chunk = (k2 * 4 + quad) ^ ((l16 >> 1) & 7);
                pf[st][k2] = *(const bf16x8*)&Ps[wave][st][l16 * 64 + chunk * 8];
            }

        // O += P V (both subtiles share each V fragment)
#pragma unroll
        for (int k2 = 0; k2 < 2; ++k2)
#pragma unroll
            for (int ni = 0; ni < 8; ++ni) {
                int r = ni * 16 + l16;
                int c = (k2 * 4 + quad) ^ (l16 & 7) ^ (((l16 >> 3) & 1) << 2);
                bf16x8 vf = *(const bf16x8*)&VTs[r * 64 + c * 8];
                o0[ni] = mfma_bf16(pf[0][k2], vf, o0[ni]);
                o1[ni] = mfma_bf16(pf[1][k2], vf, o1[ni]);
            }
        __syncthreads();
    }

    // reduce row-sums l across the quad's 16 lanes (once)
#pragma unroll
    for (int off = 1; off < 16; off <<= 1) {
#pragma unroll
        for (int j = 0; j < 4; ++j) {
            lac0[j] += __shfl_xor(lac0[j], off);
            lac1[j] += __shfl_xor(lac1[j], off);
        }
    }

#pragma unroll
    for (int st = 0; st < 2; ++st) {
#pragma unroll
        for (int j = 0; j < 4; ++j) {
            float rl = 1.0f / (st ? lac1[j] : lac0[j]);
            int s_row = q0 + st * 16 + quad * 4 + j;
#pragma unroll
            for (int ni = 0; ni < 8; ++ni) {
                float v = (st ? o1[ni][j] : o0[ni][j]) * rl;
                int col = h * HD + ni * 16 + l16;
                ao[(long)s_row * DIM + col] = (bf16_t)v;
                if (s_row >= SIMG) out_txt[(long)(s_row - SIMG) * DIM + col] = v;
            }
        }
    }
}

// ---------------- launch ----------------
extern "C" void kernel_launch(void* const* d_in, const int* in_sizes, int n_in,
                              void* d_out, int out_size, void* d_ws, size_t ws_size,
                              hipStream_t stream) {
    const float* hid = (const float*)d_in[0];
    const float* enc = (const float*)d_in[1];
    const float* rope_cos = (const float*)d_in[2];
    const float* rope_sin = (const float*)d_in[3];
    const float* wq = (const float*)d_in[4];
    const float* bq = (const float*)d_in[5];
    const float* wk = (const float*)d_in[6];
    const float* bk = (const float*)d_in[7];
    const float* wv = (const float*)d_in[8];
    const float* bv = (const float*)d_in[9];
    const float* nqw = (const float*)d_in[10];
    const float* nkw = (const float*)d_in[11];
    const float* wo = (const float*)d_in[12];
    const float* bo = (const float*)d_in[13];
    float* out = (float*)d_out;

    char* ws = (char*)d_ws;
    bf16_t* xb   = (bf16_t*)(ws);                 // 2304*3072 bf16
    bf16_t* wTq  = (bf16_t*)(ws + 14155776L);     // 3*3072*3072 bf16
    bf16_t* woT  = (bf16_t*)(ws + 70778880L);     // 3072*3072 bf16
    float*  bcat = (float*) (ws + 89653248L);     // 9216 f32
    bf16_t* qkvb = (bf16_t*)(ws + 89690112L);     // 2304*9216 bf16
    bf16_t* qb   = (bf16_t*)(ws + 132157440L);    // 24*2304*128 bf16
    bf16_t* kbuf = (bf16_t*)(ws + 146313216L);
    bf16_t* vT   = (bf16_t*)(ws + 160468992L);
    bf16_t* ao   = (bf16_t*)(ws + 174624768L);    // 2304*3072 bf16

    k_convert_x<<<6912, 256, 0, stream>>>(hid, enc, xb);
    dim3 tg(48, 48);
    k_wT<<<tg, 256, 0, stream>>>(wq, wTq);
    k_wT<<<tg, 256, 0, stream>>>(wk, wTq + 3072L * 3072);
    k_wT<<<tg, 256, 0, stream>>>(wv, wTq + 2 * 3072L * 3072);
    k_wT<<<tg, 256, 0, stream>>>(wo, woT);
    k_bias<<<36, 256, 0, stream>>>(bq, bk, bv, bcat);
    k_gemm_bt<<<dim3(72, 18), 256, 0, stream>>>(xb, wTq, bcat, qkvb, (float*)nullptr, S_ALL, NQKV, DIM);
    k_qk_epi<<<27648, 256, 0, stream>>>(qkvb, rope_cos, rope_sin, nqw, nkw, qb, kbuf);
    k_vT<<<dim3(36, 2, 24), 256, 0, stream>>>(qkvb, vT);
    k_attn<<<dim3(18, 24), 256, 0, stream>>>(qb, kbuf, vT, ao, out + (long)SIMG * DIM);
    k_gemm_bt<<<dim3(24, 16), 256, 0, stream>>>(ao, woT, bo, (bf16_t*)nullptr, out, SIMG, DIM, DIM);
}

// Round 3
// 573.413 us; speedup vs baseline: 1.5080x; 1.1253x over previous
//
#include <hip/hip_runtime.h>
#include <cstdint>

typedef __bf16 bf16_t;
typedef bf16_t bf16x8 __attribute__((ext_vector_type(8)));
typedef bf16_t bf16x4 __attribute__((ext_vector_type(4)));
typedef float  floatx4 __attribute__((ext_vector_type(4)));

#define S_ALL 2304
#define SIMG  2048
#define NH    24
#define HD    128
#define DIM   3072
#define NQKV  9216

// exp(s-12) computed as exp2(s*log2e - 12*log2e); log2e folded into q pre-scale
#define SHIFT2 17.312340490667562f
#define QSCALE 0.12751744f   /* (1/sqrt(128)) * log2(e) */

typedef __attribute__((address_space(1))) void* gp1_t;
typedef __attribute__((address_space(3))) void* lp3_t;

__device__ __forceinline__ void async16(const void* g, void* l) {
    __builtin_amdgcn_global_load_lds((gp1_t)(g), (lp3_t)(l), 16, 0, 0);
}
__device__ __forceinline__ floatx4 mfma_bf16(bf16x8 a, bf16x8 b, floatx4 c) {
    return __builtin_amdgcn_mfma_f32_16x16x32_bf16(a, b, c, 0, 0, 0);
}

// ---------------- x concat + fp32->bf16 ----------------
__global__ __launch_bounds__(256) void k_convert_x(const float* __restrict__ hid,
                                                   const float* __restrict__ enc,
                                                   bf16_t* __restrict__ xb) {
    long i = ((long)blockIdx.x * 256 + threadIdx.x) * 4;
    const long HN = (long)SIMG * DIM;
    float4 f = (i < HN) ? *(const float4*)(hid + i) : *(const float4*)(enc + (i - HN));
    bf16x4 o;
    o[0] = (bf16_t)f.x; o[1] = (bf16_t)f.y; o[2] = (bf16_t)f.z; o[3] = (bf16_t)f.w;
    *(bf16x4*)(xb + i) = o;
}

// ---------------- weight transpose-convert: 4 weights in one launch (blockIdx.z) ----------------
__global__ __launch_bounds__(256) void k_wT4(const float* __restrict__ wq, const float* __restrict__ wk,
                                             const float* __restrict__ wv, const float* __restrict__ wo,
                                             bf16_t* __restrict__ wTq, bf16_t* __restrict__ woT) {
    __shared__ __align__(16) bf16_t T[64][72];
    int z = blockIdx.z;
    const float* W = (z == 0) ? wq : (z == 1) ? wk : (z == 2) ? wv : wo;
    bf16_t* Wt = (z < 3) ? (wTq + (long)z * DIM * DIM) : woT;
    int r0 = blockIdx.x * 64, c0 = blockIdx.y * 64;
    int tid = threadIdx.x;
    int lr = tid >> 2, lc = (tid & 3) * 16;
    const float* src = W + (long)(r0 + lr) * DIM + c0 + lc;
#pragma unroll
    for (int i = 0; i < 16; i += 4) {
        float4 f = *(const float4*)(src + i);
        T[lr][lc + i + 0] = (bf16_t)f.x;
        T[lr][lc + i + 1] = (bf16_t)f.y;
        T[lr][lc + i + 2] = (bf16_t)f.z;
        T[lr][lc + i + 3] = (bf16_t)f.w;
    }
    __syncthreads();
    bf16x8 a, b;
#pragma unroll
    for (int i = 0; i < 8; i++) a[i] = T[lc + i][lr];
#pragma unroll
    for (int i = 0; i < 8; i++) b[i] = T[lc + 8 + i][lr];
    bf16_t* dst = Wt + (long)(c0 + lr) * DIM + r0 + lc;
    *(bf16x8*)dst = a;
    *(bf16x8*)(dst + 8) = b;
}

// ---------------- bias concat ----------------
__global__ __launch_bounds__(256) void k_bias(const float* __restrict__ bq, const float* __restrict__ bk,
                                              const float* __restrict__ bv, float* __restrict__ bcat) {
    int i = blockIdx.x * 256 + threadIdx.x;
    float v = (i < DIM) ? bq[i] : (i < 2 * DIM ? bk[i - DIM] : bv[i - 2 * DIM]);
    bcat[i] = v;
}

// ---------------- GEMM: C[M,N] = A[M,K] * Bt[N,K]^T + bias ----------------
// 128x128 tile, XOR-swizzled LDS (16B chunk c of row r at slot c^(r&7)):
// staging applies inverse XOR on the global source; reads use chunk (ks*4+quad)^(l16&7).
// Wave b128 read covers all 32 banks at exactly 8 dwords/bank -> conflict-free.
__global__ __launch_bounds__(256) void k_gemm_bt(const bf16_t* __restrict__ A,
                                                 const bf16_t* __restrict__ Bt,
                                                 const float* __restrict__ bias,
                                                 bf16_t* __restrict__ Cb, float* __restrict__ Cf,
                                                 int M, int N, int K) {
    __shared__ __align__(16) bf16_t As[128 * 64];
    __shared__ __align__(16) bf16_t Bs[128 * 64];
    int tid = threadIdx.x;
    int wave = tid >> 6, lane = tid & 63;
    int quad = lane >> 4, l16 = lane & 15;
    long m0 = (long)blockIdx.y * 128, n0 = (long)blockIdx.x * 128;
    int wm = (wave >> 1) * 64, wn = (wave & 1) * 64;

    floatx4 zero = {0.f, 0.f, 0.f, 0.f};
    floatx4 acc[4][4];
#pragma unroll
    for (int i = 0; i < 4; i++)
#pragma unroll
        for (int j = 0; j < 4; j++) acc[i][j] = zero;

    int kxor = ((lane & 7) ^ ((lane >> 3) & 7)) * 8;  // swizzled source k-offset (elements)
    const bf16_t* Ag = A + (m0 + wave * 32 + (lane >> 3)) * K + kxor;
    const bf16_t* Bg = Bt + (n0 + wave * 32 + (lane >> 3)) * K + kxor;
    char* AsB = (char*)As + wave * 4096;
    char* BsB = (char*)Bs + wave * 4096;

    for (int k0 = 0; k0 < K; k0 += 64) {
#pragma unroll
        for (int c2 = 0; c2 < 4; ++c2) {
            async16(Ag + (long)c2 * 8 * K + k0, AsB + c2 * 1024);
            async16(Bg + (long)c2 * 8 * K + k0, BsB + c2 * 1024);
        }
        __syncthreads();
#pragma unroll
        for (int ks = 0; ks < 2; ++ks) {
            bf16x8 af[4], bfr[4];
            int ch = 0;
#pragma unroll
            for (int i = 0; i < 4; i++) {
                ch = ((ks * 4 + quad) ^ (l16 & 7)) * 8;
                af[i] = *(const bf16x8*)&As[(wm + i * 16 + l16) * 64 + ch];
            }
#pragma unroll
            for (int i = 0; i < 4; i++)
                bfr[i] = *(const bf16x8*)&Bs[(wn + i * 16 + l16) * 64 + ch];
#pragma unroll
            for (int i = 0; i < 4; i++)
#pragma unroll
                for (int j = 0; j < 4; j++) acc[i][j] = mfma_bf16(af[i], bfr[j], acc[i][j]);
        }
        __syncthreads();
    }

#pragma unroll
    for (int i = 0; i < 4; i++) {
        long rowb = m0 + wm + i * 16 + quad * 4;
#pragma unroll
        for (int j = 0; j < 4; j++) {
            long col = n0 + wn + j * 16 + l16;
            float bv = bias ? bias[col] : 0.0f;
#pragma unroll
            for (int r = 0; r < 4; r++) {
                float v = acc[i][j][r] + bv;
                long idx = (rowb + r) * N + col;
                if (Cb) Cb[idx] = (bf16_t)v;
                else    Cf[idx] = v;
            }
        }
    }
}

// ---------------- q/k epilogue: RMSNorm + RoPE + (q) scale*log2e ----------------
__global__ __launch_bounds__(256) void k_qk_epi(const bf16_t* __restrict__ qkvb,
                                                const float* __restrict__ rope_cos,
                                                const float* __restrict__ rope_sin,
                                                const float* __restrict__ nqw,
                                                const float* __restrict__ nkw,
                                                bf16_t* __restrict__ qo, bf16_t* __restrict__ ko) {
    int tid = threadIdx.x, wave = tid >> 6, lane = tid & 63;
    int row_id = blockIdx.x * 4 + wave;  // 0 .. 110591
    int t = row_id / (S_ALL * NH);
    int rem = row_id - t * (S_ALL * NH);
    int h = rem / S_ALL;
    int s = rem - h * S_ALL;
    const bf16_t* src = qkvb + (long)s * NQKV + t * DIM + h * HD + lane * 2;
    float x0 = (float)src[0], x1 = (float)src[1];
    float ss = x0 * x0 + x1 * x1;
#pragma unroll
    for (int off = 1; off < 64; off <<= 1) ss += __shfl_xor(ss, off);
    float r = rsqrtf(ss * (1.0f / 128.0f) + 1e-6f);
    const float* w = t ? nkw : nqw;
    x0 *= r * w[lane * 2];
    x1 *= r * w[lane * 2 + 1];
    if (s < SIMG) {
        float c = rope_cos[s * HD + lane * 2];
        float sn = rope_sin[s * HD + lane * 2];
        float y0 = x0 * c - x1 * sn;
        float y1 = x1 * c + x0 * sn;
        x0 = y0; x1 = y1;
    }
    if (t == 0) { x0 *= QSCALE; x1 *= QSCALE; }
    bf16_t* dst = (t ? ko : qo) + (long)h * S_ALL * HD + (long)s * HD + lane * 2;
    dst[0] = (bf16_t)x0;
    dst[1] = (bf16_t)x1;
}

// ---------------- V transpose: qkvb v-part [s][d] per head -> vT [h][d][s] ----------------
__global__ __launch_bounds__(256) void k_vT(const bf16_t* __restrict__ qkvb, bf16_t* __restrict__ vT) {
    __shared__ __align__(16) bf16_t T[64][72];
    int h = blockIdx.z;
    int s0 = blockIdx.x * 64, d0 = blockIdx.y * 64;
    int tid = threadIdx.x, lr = tid >> 2, lc = (tid & 3) * 16;
    const bf16_t* src = qkvb + (long)(s0 + lr) * NQKV + 2 * DIM + h * HD + d0 + lc;
    bf16x8 a = *(const bf16x8*)src, b = *(const bf16x8*)(src + 8);
#pragma unroll
    for (int i = 0; i < 8; i++) { T[lr][lc + i] = a[i]; T[lr][lc + 8 + i] = b[i]; }
    __syncthreads();
    bf16x8 c, d;
#pragma unroll
    for (int i = 0; i < 8; i++) c[i] = T[lc + i][lr];
#pragma unroll
    for (int i = 0; i < 8; i++) d[i] = T[lc + 8 + i][lr];
    bf16_t* dst = vT + (long)h * HD * S_ALL + (long)(d0 + lr) * S_ALL + s0 + lc;
    *(bf16x8*)dst = c;
    *(bf16x8*)(dst + 8) = d;
}

// ---------------- flash attention: swizzled LDS, fixed-shift softmax ----------------
// grid (18, 24): 128 q-rows/block, 4 waves x 32 q-rows (2 subtiles of 16); K-blocks of 64.
__global__ __launch_bounds__(256, 2) void k_attn(const bf16_t* __restrict__ q,
                                                 const bf16_t* __restrict__ k,
                                                 const bf16_t* __restrict__ vT,
                                                 bf16_t* __restrict__ ao,
                                                 float* __restrict__ out_txt) {
    __shared__ __align__(16) bf16_t Ks[64 * 128];       // 16 KB
    __shared__ __align__(16) bf16_t VTs[128 * 64];      // 16 KB
    __shared__ __align__(16) bf16_t Ps[4][2][16 * 64];  // 16 KB (per wave, per subtile)
    int tid = threadIdx.x, wave = tid >> 6, lane = tid & 63;
    int quad = lane >> 4, l16 = lane & 15;
    int h = blockIdx.y;
    int q0 = blockIdx.x * 128 + wave * 32;
    const long hbase = (long)h * S_ALL * HD;
    const char* kgb = (const char*)(k + hbase);
    const char* vgb = (const char*)(vT + hbase);

    int koffB[4], voffB[4], slotB[4];
#pragma unroll
    for (int c2 = 0; c2 < 4; ++c2) {
        int L = (wave * 4 + c2) * 64 + lane;
        slotB[c2] = L;
        int rk = L >> 4, ck = (L & 15) ^ (rk & 15);
        koffB[c2] = rk * 256 + ck * 16;
        int rv = L >> 3, cv = (L & 7) ^ (rv & 7) ^ (((rv >> 3) & 1) << 2);
        voffB[c2] = rv * (S_ALL * 2) + cv * 16;
    }

    bf16x8 qf[2][4];
#pragma unroll
    for (int st = 0; st < 2; ++st) {
        const bf16_t* qp = q + hbase + (long)(q0 + st * 16 + l16) * HD + quad * 8;
#pragma unroll
        for (int ks = 0; ks < 4; ++ks) qf[st][ks] = *(const bf16x8*)(qp + ks * 32);
    }

    floatx4 zero = {0.f, 0.f, 0.f, 0.f};
    floatx4 o0[8], o1[8];
#pragma unroll
    for (int ni = 0; ni < 8; ++ni) { o0[ni] = zero; o1[ni] = zero; }
    floatx4 lac0 = zero, lac1 = zero;

    for (int kb = 0; kb < S_ALL / 64; ++kb) {
        const char* kg = kgb + (long)kb * 16384;
        const char* vg = vgb + kb * 128;
#pragma unroll
        for (int c2 = 0; c2 < 4; ++c2) {
            async16(kg + koffB[c2], (char*)Ks + slotB[c2] * 16);
            async16(vg + voffB[c2], (char*)VTs + slotB[c2] * 16);
        }
        __syncthreads();

        floatx4 s0[4], s1[4];
#pragma unroll
        for (int ni = 0; ni < 4; ++ni) { s0[ni] = zero; s1[ni] = zero; }
#pragma unroll
        for (int ks = 0; ks < 4; ++ks)
#pragma unroll
            for (int ni = 0; ni < 4; ++ni) {
                int slot = (ni * 16 + l16) * 16 + ((ks * 4 + quad) ^ l16);
                bf16x8 kf = *(const bf16x8*)&Ks[slot * 8];
                s0[ni] = mfma_bf16(qf[0][ks], kf, s0[ni]);
                s1[ni] = mfma_bf16(qf[1][ks], kf, s1[ni]);
            }

#pragma unroll
        for (int st = 0; st < 2; ++st) {
#pragma unroll
            for (int ni = 0; ni < 4; ++ni) {
                floatx4 sv = st ? s1[ni] : s0[ni];
                floatx4 p;
#pragma unroll
                for (int j = 0; j < 4; ++j) p[j] = __builtin_amdgcn_exp2f(sv[j] - SHIFT2);
                if (st) lac1 += p; else lac0 += p;
#pragma unroll
                for (int j = 0; j < 4; ++j) {
                    int r = quad * 4 + j;
                    int chunk = ((ni * 16 + l16) >> 3) ^ ((r >> 1) & 7);
                    Ps[wave][st][r * 64 + chunk * 8 + (l16 & 7)] = (bf16_t)p[j];
                }
            }
        }

        bf16x8 pf[2][2];
#pragma unroll
        for (int st = 0; st < 2; ++st)
#pragma unroll
            for (int k2 = 0; k2 < 2; ++k2) {
                int chunk = (k2 * 4 + quad) ^ ((l16 >> 1) & 7);
                pf[st][k2] = *(const bf16x8*)&Ps[wave][st][l16 * 64 + chunk * 8];
            }

#pragma unroll
        for (int k2 = 0; k2 < 2; ++k2)
#pragma unroll
            for (int ni = 0; ni < 8; ++ni) {
                int r = ni * 16 + l16;
                int c = (k2 * 4 + quad) ^ (l16 & 7) ^ (((l16 >> 3) & 1) << 2);
                bf16x8 vf = *(const bf16x8*)&VTs[r * 64 + c * 8];
                o0[ni] = mfma_bf16(pf[0][k2], vf, o0[ni]);
                o1[ni] = mfma_bf16(pf[1][k2], vf, o1[ni]);
            }
        __syncthreads();
    }

#pragma unroll
    for (int off = 1; off < 16; off <<= 1) {
#pragma unroll
        for (int j = 0; j < 4; ++j) {
            lac0[j] += __shfl_xor(lac0[j], off);
            lac1[j] += __shfl_xor(lac1[j], off);
        }
    }

#pragma unroll
    for (int st = 0; st < 2; ++st) {
#pragma unroll
        for (int j = 0; j < 4; ++j) {
            float rl = 1.0f / (st ? lac1[j] : lac0[j]);
            int s_row = q0 + st * 16 + quad * 4 + j;
#pragma unroll
            for (int ni = 0; ni < 8; ++ni) {
                float v = (st ? o1[ni][j] : o0[ni][j]) * rl;
                int col = h * HD + ni * 16 + l16;
                ao[(long)s_row * DIM + col] = (bf16_t)v;
                if (s_row >= SIMG) out_txt[(long)(s_row - SIMG) * DIM + col] = v;
            }
        }
    }
}

// ---------------- launch ----------------
extern "C" void kernel_launch(void* const* d_in, const int* in_sizes, int n_in,
                              void* d_out, int out_size, void* d_ws, size_t ws_size,
                              hipStream_t stream) {
    const float* hid = (const float*)d_in[0];
    const float* enc = (const float*)d_in[1];
    const float* rope_cos = (const float*)d_in[2];
    const float* rope_sin = (const float*)d_in[3];
    const float* wq = (const float*)d_in[4];
    const float* bq = (const float*)d_in[5];
    const float* wk = (const float*)d_in[6];
    const float* bk = (const float*)d_in[7];
    const float* wv = (const float*)d_in[8];
    const float* bv = (const float*)d_in[9];
    const float* nqw = (const float*)d_in[10];
    const float* nkw = (const float*)d_in[11];
    const float* wo = (const float*)d_in[12];
    const float* bo = (const float*)d_in[13];
    float* out = (float*)d_out;

    char* ws = (char*)d_ws;
    bf16_t* xb   = (bf16_t*)(ws);                 // 2304*3072 bf16
    bf16_t* wTq  = (bf16_t*)(ws + 14155776L);     // 3*3072*3072 bf16
    bf16_t* woT  = (bf16_t*)(ws + 70778880L);     // 3072*3072 bf16
    float*  bcat = (float*) (ws + 89653248L);     // 9216 f32
    bf16_t* qkvb = (bf16_t*)(ws + 89690112L);     // 2304*9216 bf16
    bf16_t* qb   = (bf16_t*)(ws + 132157440L);    // 24*2304*128 bf16
    bf16_t* kbuf = (bf16_t*)(ws + 146313216L);
    bf16_t* vT   = (bf16_t*)(ws + 160468992L);
    bf16_t* ao   = (bf16_t*)(ws + 174624768L);    // 2304*3072 bf16

    k_convert_x<<<6912, 256, 0, stream>>>(hid, enc, xb);
    k_wT4<<<dim3(48, 48, 4), 256, 0, stream>>>(wq, wk, wv, wo, wTq, woT);
    k_bias<<<36, 256, 0, stream>>>(bq, bk, bv, bcat);
    k_gemm_bt<<<dim3(72, 18), 256, 0, stream>>>(xb, wTq, bcat, qkvb, (float*)nullptr, S_ALL, NQKV, DIM);
    k_qk_epi<<<27648, 256, 0, stream>>>(qkvb, rope_cos, rope_sin, nqw, nkw, qb, kbuf);
    k_vT<<<dim3(36, 2, 24), 256, 0, stream>>>(qkvb, vT);
    k_attn<<<dim3(18, 24), 256, 0, stream>>>(qb, kbuf, vT, ao, out + (long)SIMG * DIM);
    k_gemm_bt<<<dim3(24, 16), 256, 0, stream>>>(ao, woT, bo, (bf16_t*)nullptr, out, SIMG, DIM, DIM);
}

// Round 4
// 562.411 us; speedup vs baseline: 1.5375x; 1.0196x over previous
//
#include <hip/hip_runtime.h>
#include <cstdint>

typedef __bf16 bf16_t;
typedef bf16_t bf16x8 __attribute__((ext_vector_type(8)));
typedef bf16_t bf16x4 __attribute__((ext_vector_type(4)));
typedef float  floatx4 __attribute__((ext_vector_type(4)));

#define S_ALL 2304
#define SIMG  2048
#define NH    24
#define HD    128
#define DIM   3072
#define NQKV  9216

// exp(s-12) computed as exp2(s*log2e - 12*log2e); log2e folded into q pre-scale
#define SHIFT2 17.312340490667562f
#define QSCALE 0.12751744f   /* (1/sqrt(128)) * log2(e) */

typedef __attribute__((address_space(1))) void* gp1_t;
typedef __attribute__((address_space(3))) void* lp3_t;

__device__ __forceinline__ void async16(const void* g, void* l) {
    __builtin_amdgcn_global_load_lds((gp1_t)(g), (lp3_t)(l), 16, 0, 0);
}
__device__ __forceinline__ floatx4 mfma_bf16(bf16x8 a, bf16x8 b, floatx4 c) {
    return __builtin_amdgcn_mfma_f32_16x16x32_bf16(a, b, c, 0, 0, 0);
}

// ---------------- x concat + fp32->bf16 ----------------
__global__ __launch_bounds__(256) void k_convert_x(const float* __restrict__ hid,
                                                   const float* __restrict__ enc,
                                                   bf16_t* __restrict__ xb) {
    long i = ((long)blockIdx.x * 256 + threadIdx.x) * 4;
    const long HN = (long)SIMG * DIM;
    float4 f = (i < HN) ? *(const float4*)(hid + i) : *(const float4*)(enc + (i - HN));
    bf16x4 o;
    o[0] = (bf16_t)f.x; o[1] = (bf16_t)f.y; o[2] = (bf16_t)f.z; o[3] = (bf16_t)f.w;
    *(bf16x4*)(xb + i) = o;
}

// ---------------- weight transpose-convert: 4 weights in one launch (blockIdx.z) ----------------
__global__ __launch_bounds__(256) void k_wT4(const float* __restrict__ wq, const float* __restrict__ wk,
                                             const float* __restrict__ wv, const float* __restrict__ wo,
                                             bf16_t* __restrict__ wTq, bf16_t* __restrict__ woT) {
    __shared__ __align__(16) bf16_t T[64][72];
    int z = blockIdx.z;
    const float* W = (z == 0) ? wq : (z == 1) ? wk : (z == 2) ? wv : wo;
    bf16_t* Wt = (z < 3) ? (wTq + (long)z * DIM * DIM) : woT;
    int r0 = blockIdx.x * 64, c0 = blockIdx.y * 64;
    int tid = threadIdx.x;
    int lr = tid >> 2, lc = (tid & 3) * 16;
    const float* src = W + (long)(r0 + lr) * DIM + c0 + lc;
#pragma unroll
    for (int i = 0; i < 16; i += 4) {
        float4 f = *(const float4*)(src + i);
        T[lr][lc + i + 0] = (bf16_t)f.x;
        T[lr][lc + i + 1] = (bf16_t)f.y;
        T[lr][lc + i + 2] = (bf16_t)f.z;
        T[lr][lc + i + 3] = (bf16_t)f.w;
    }
    __syncthreads();
    bf16x8 a, b;
#pragma unroll
    for (int i = 0; i < 8; i++) a[i] = T[lc + i][lr];
#pragma unroll
    for (int i = 0; i < 8; i++) b[i] = T[lc + 8 + i][lr];
    bf16_t* dst = Wt + (long)(c0 + lr) * DIM + r0 + lc;
    *(bf16x8*)dst = a;
    *(bf16x8*)(dst + 8) = b;
}

// ---------------- fused QKV GEMM + bias + RMSNorm + RoPE + V-transpose ----------------
// C[M=2304, N=9216] = x[2304,3072] * Wt[9216,3072]^T. Each 128-col tile is one (t,h):
// t = bx/24 (0=q,1=k,2=v), h = bx%24. Epilogue does the per-head postprocessing in-register
// and writes q/k as [h][s][d] (bf16) and v transposed as [h][d][s] via swizzled LDS.
__global__ __launch_bounds__(256) void k_gemm_qkv(const bf16_t* __restrict__ A,
                                                  const bf16_t* __restrict__ Bt,
                                                  const float* __restrict__ bq_,
                                                  const float* __restrict__ bk_,
                                                  const float* __restrict__ bv_,
                                                  const float* __restrict__ rope_cos,
                                                  const float* __restrict__ rope_sin,
                                                  const float* __restrict__ nqw,
                                                  const float* __restrict__ nkw,
                                                  bf16_t* __restrict__ qo,
                                                  bf16_t* __restrict__ ko,
                                                  bf16_t* __restrict__ vT) {
    __shared__ __align__(16) char smem[33 * 1024];
    bf16_t* As = (bf16_t*)smem;               // 16 KB
    bf16_t* Bs = (bf16_t*)(smem + 16384);     // 16 KB
    float* ssq = (float*)(smem + 32768);      // 1 KB: [2][64][2]
    int tid = threadIdx.x;
    int wave = tid >> 6, lane = tid & 63;
    int quad = lane >> 4, l16 = lane & 15;
    long m0 = (long)blockIdx.y * 128, n0 = (long)blockIdx.x * 128;
    int t = blockIdx.x / 24, h = blockIdx.x % 24;
    int wm = (wave >> 1) * 64, wn = (wave & 1) * 64;

    floatx4 zero = {0.f, 0.f, 0.f, 0.f};
    floatx4 acc[4][4];
#pragma unroll
    for (int i = 0; i < 4; i++)
#pragma unroll
        for (int j = 0; j < 4; j++) acc[i][j] = zero;

    int kxor = ((lane & 7) ^ ((lane >> 3) & 7)) * 8;
    const bf16_t* Ag = A + (m0 + wave * 32 + (lane >> 3)) * DIM + kxor;
    const bf16_t* Bg = Bt + (n0 + wave * 32 + (lane >> 3)) * DIM + kxor;
    char* AsB = (char*)As + wave * 4096;
    char* BsB = (char*)Bs + wave * 4096;

    for (int k0 = 0; k0 < DIM; k0 += 64) {
#pragma unroll
        for (int c2 = 0; c2 < 4; ++c2) {
            async16(Ag + (long)c2 * 8 * DIM + k0, AsB + c2 * 1024);
            async16(Bg + (long)c2 * 8 * DIM + k0, BsB + c2 * 1024);
        }
        __syncthreads();
#pragma unroll
        for (int ks = 0; ks < 2; ++ks) {
            bf16x8 af[4], bfr[4];
            int ch = ((ks * 4 + quad) ^ (l16 & 7)) * 8;
#pragma unroll
            for (int i = 0; i < 4; i++)
                af[i] = *(const bf16x8*)&As[(wm + i * 16 + l16) * 64 + ch];
#pragma unroll
            for (int i = 0; i < 4; i++)
                bfr[i] = *(const bf16x8*)&Bs[(wn + i * 16 + l16) * 64 + ch];
#pragma unroll
            for (int i = 0; i < 4; i++)
#pragma unroll
                for (int j = 0; j < 4; j++) acc[i][j] = mfma_bf16(af[i], bfr[j], acc[i][j]);
        }
        __syncthreads();
    }

    int dcol[4];
#pragma unroll
    for (int j = 0; j < 4; j++) dcol[j] = wn + j * 16 + l16;

    if (t == 2) {
        // ---- V: bias add + LDS transpose -> vT[h][d][s] ----
        float bias4[4];
#pragma unroll
        for (int j = 0; j < 4; j++) bias4[j] = bv_[h * HD + dcol[j]];
        // swizzled store: (d, s_local) -> chunk d*16 + ((s_local>>3) ^ (d&15)), byte (s_local&7)*2
        char* vbuf = smem;  // reuse As+Bs (32 KB), safe after final loop barrier
#pragma unroll
        for (int i = 0; i < 4; i++)
#pragma unroll
            for (int r = 0; r < 4; r++) {
                int s_l = wm + i * 16 + quad * 4 + r;
#pragma unroll
                for (int j = 0; j < 4; j++) {
                    int d = dcol[j];
                    int chunk = d * 16 + ((s_l >> 3) ^ (d & 15));
                    *(bf16_t*)(vbuf + chunk * 16 + (s_l & 7) * 2) = (bf16_t)(acc[i][j][r] + bias4[j]);
                }
            }
        __syncthreads();
        int d = tid >> 1, sh = tid & 1;
        bf16_t* dstv = vT + (long)h * HD * S_ALL + (long)d * S_ALL + m0 + sh * 64;
#pragma unroll
        for (int k8 = 0; k8 < 8; ++k8) {
            int s8 = sh * 8 + k8;
            bf16x8 frag = *(const bf16x8*)(vbuf + (d * 16 + (s8 ^ (d & 15))) * 16);
            *(bf16x8*)(dstv + k8 * 8) = frag;
        }
    } else {
        // ---- Q/K: bias + RMSNorm + RoPE (+QSCALE for q), write [h][s][d] ----
        const float* bp = t ? bk_ : bq_;
        const float* nw = t ? nkw : nqw;
        float bias4[4], wv4[4];
#pragma unroll
        for (int j = 0; j < 4; j++) {
            bias4[j] = bp[h * HD + dcol[j]];
            wv4[j] = nw[dcol[j]];
        }
        int wmh = wm >> 6, wnh = wn >> 6;
#pragma unroll
        for (int i = 0; i < 4; i++)
#pragma unroll
            for (int r = 0; r < 4; r++) {
                float s2 = 0.f;
#pragma unroll
                for (int j = 0; j < 4; j++) {
                    float v = acc[i][j][r] + bias4[j];
                    acc[i][j][r] = v;
                    s2 += v * v;
                }
                s2 += __shfl_xor(s2, 1);
                s2 += __shfl_xor(s2, 2);
                s2 += __shfl_xor(s2, 4);
                s2 += __shfl_xor(s2, 8);
                if (l16 == 0) ssq[(wmh * 64 + i * 16 + quad * 4 + r) * 2 + wnh] = s2;
            }
        __syncthreads();
        bf16_t* dst = (t ? ko : qo) + (long)h * S_ALL * HD;
        bool do_rope = (m0 < SIMG);  // block-uniform: 128-row tiles align to the 2048 boundary
#pragma unroll
        for (int i = 0; i < 4; i++)
#pragma unroll
            for (int r = 0; r < 4; r++) {
                int row = i * 16 + quad * 4 + r;
                int s_abs = (int)m0 + wm + row;
                float tot = ssq[(wmh * 64 + row) * 2] + ssq[(wmh * 64 + row) * 2 + 1];
                float rms = rsqrtf(tot * (1.0f / 128.0f) + 1e-6f);
                float y[4];
#pragma unroll
                for (int j = 0; j < 4; j++) y[j] = acc[i][j][r] * rms * wv4[j];
                if (do_rope) {
                    const float* cp = rope_cos + (long)s_abs * HD;
                    const float* sp = rope_sin + (long)s_abs * HD;
#pragma unroll
                    for (int j = 0; j < 4; j++) {
                        float c = cp[dcol[j]], sn = sp[dcol[j]];
                        float px = __shfl_xor(y[j], 1);
                        y[j] = y[j] * c + ((l16 & 1) ? px : -px) * sn;
                    }
                }
#pragma unroll
                for (int j = 0; j < 4; j++) {
                    float v = t ? y[j] : y[j] * QSCALE;
                    dst[(long)s_abs * HD + dcol[j]] = (bf16_t)v;
                }
            }
    }
}

// ---------------- GEMM: C[M,N] = A[M,K] * Bt[N,K]^T + bias (O-proj) ----------------
__global__ __launch_bounds__(256) void k_gemm_bt(const bf16_t* __restrict__ A,
                                                 const bf16_t* __restrict__ Bt,
                                                 const float* __restrict__ bias,
                                                 bf16_t* __restrict__ Cb, float* __restrict__ Cf,
                                                 int M, int N, int K) {
    __shared__ __align__(16) bf16_t As[128 * 64];
    __shared__ __align__(16) bf16_t Bs[128 * 64];
    int tid = threadIdx.x;
    int wave = tid >> 6, lane = tid & 63;
    int quad = lane >> 4, l16 = lane & 15;
    long m0 = (long)blockIdx.y * 128, n0 = (long)blockIdx.x * 128;
    int wm = (wave >> 1) * 64, wn = (wave & 1) * 64;

    floatx4 zero = {0.f, 0.f, 0.f, 0.f};
    floatx4 acc[4][4];
#pragma unroll
    for (int i = 0; i < 4; i++)
#pragma unroll
        for (int j = 0; j < 4; j++) acc[i][j] = zero;

    int kxor = ((lane & 7) ^ ((lane >> 3) & 7)) * 8;
    const bf16_t* Ag = A + (m0 + wave * 32 + (lane >> 3)) * K + kxor;
    const bf16_t* Bg = Bt + (n0 + wave * 32 + (lane >> 3)) * K + kxor;
    char* AsB = (char*)As + wave * 4096;
    char* BsB = (char*)Bs + wave * 4096;

    for (int k0 = 0; k0 < K; k0 += 64) {
#pragma unroll
        for (int c2 = 0; c2 < 4; ++c2) {
            async16(Ag + (long)c2 * 8 * K + k0, AsB + c2 * 1024);
            async16(Bg + (long)c2 * 8 * K + k0, BsB + c2 * 1024);
        }
        __syncthreads();
#pragma unroll
        for (int ks = 0; ks < 2; ++ks) {
            bf16x8 af[4], bfr[4];
            int ch = ((ks * 4 + quad) ^ (l16 & 7)) * 8;
#pragma unroll
            for (int i = 0; i < 4; i++)
                af[i] = *(const bf16x8*)&As[(wm + i * 16 + l16) * 64 + ch];
#pragma unroll
            for (int i = 0; i < 4; i++)
                bfr[i] = *(const bf16x8*)&Bs[(wn + i * 16 + l16) * 64 + ch];
#pragma unroll
            for (int i = 0; i < 4; i++)
#pragma unroll
                for (int j = 0; j < 4; j++) acc[i][j] = mfma_bf16(af[i], bfr[j], acc[i][j]);
        }
        __syncthreads();
    }

#pragma unroll
    for (int i = 0; i < 4; i++) {
        long rowb = m0 + wm + i * 16 + quad * 4;
#pragma unroll
        for (int j = 0; j < 4; j++) {
            long col = n0 + wn + j * 16 + l16;
            float bv = bias ? bias[col] : 0.0f;
#pragma unroll
            for (int r = 0; r < 4; r++) {
                float v = acc[i][j][r] + bv;
                long idx = (rowb + r) * N + col;
                if (Cb) Cb[idx] = (bf16_t)v;
                else    Cf[idx] = v;
            }
        }
    }
}

// ---------------- flash attention: swizzled LDS, fixed-shift softmax ----------------
// grid (18, 24): 128 q-rows/block, 4 waves x 32 q-rows (2 subtiles of 16); K-blocks of 64.
__global__ __launch_bounds__(256, 2) void k_attn(const bf16_t* __restrict__ q,
                                                 const bf16_t* __restrict__ k,
                                                 const bf16_t* __restrict__ vT,
                                                 bf16_t* __restrict__ ao,
                                                 float* __restrict__ out_txt) {
    __shared__ __align__(16) bf16_t Ks[64 * 128];       // 16 KB
    __shared__ __align__(16) bf16_t VTs[128 * 64];      // 16 KB
    __shared__ __align__(16) bf16_t Ps[4][2][16 * 64];  // 16 KB (per wave, per subtile)
    int tid = threadIdx.x, wave = tid >> 6, lane = tid & 63;
    int quad = lane >> 4, l16 = lane & 15;
    int h = blockIdx.y;
    int q0 = blockIdx.x * 128 + wave * 32;
    const long hbase = (long)h * S_ALL * HD;
    const char* kgb = (const char*)(k + hbase);
    const char* vgb = (const char*)(vT + hbase);

    int koffB[4], voffB[4], slotB[4];
#pragma unroll
    for (int c2 = 0; c2 < 4; ++c2) {
        int L = (wave * 4 + c2) * 64 + lane;
        slotB[c2] = L;
        int rk = L >> 4, ck = (L & 15) ^ (rk & 15);
        koffB[c2] = rk * 256 + ck * 16;
        int rv = L >> 3, cv = (L & 7) ^ (rv & 7) ^ (((rv >> 3) & 1) << 2);
        voffB[c2] = rv * (S_ALL * 2) + cv * 16;
    }

    bf16x8 qf[2][4];
#pragma unroll
    for (int st = 0; st < 2; ++st) {
        const bf16_t* qp = q + hbase + (long)(q0 + st * 16 + l16) * HD + quad * 8;
#pragma unroll
        for (int ks = 0; ks < 4; ++ks) qf[st][ks] = *(const bf16x8*)(qp + ks * 32);
    }

    floatx4 zero = {0.f, 0.f, 0.f, 0.f};
    floatx4 o0[8], o1[8];
#pragma unroll
    for (int ni = 0; ni < 8; ++ni) { o0[ni] = zero; o1[ni] = zero; }
    floatx4 lac0 = zero, lac1 = zero;

    for (int kb = 0; kb < S_ALL / 64; ++kb) {
        const char* kg = kgb + (long)kb * 16384;
        const char* vg = vgb + kb * 128;
#pragma unroll
        for (int c2 = 0; c2 < 4; ++c2) {
            async16(kg + koffB[c2], (char*)Ks + slotB[c2] * 16);
            async16(vg + voffB[c2], (char*)VTs + slotB[c2] * 16);
        }
        __syncthreads();

        floatx4 s0[4], s1[4];
#pragma unroll
        for (int ni = 0; ni < 4; ++ni) { s0[ni] = zero; s1[ni] = zero; }
#pragma unroll
        for (int ks = 0; ks < 4; ++ks)
#pragma unroll
            for (int ni = 0; ni < 4; ++ni) {
                int slot = (ni * 16 + l16) * 16 + ((ks * 4 + quad) ^ l16);
                bf16x8 kf = *(const bf16x8*)&Ks[slot * 8];
                s0[ni] = mfma_bf16(qf[0][ks], kf, s0[ni]);
                s1[ni] = mfma_bf16(qf[1][ks], kf, s1[ni]);
            }

#pragma unroll
        for (int st = 0; st < 2; ++st) {
#pragma unroll
            for (int ni = 0; ni < 4; ++ni) {
                floatx4 sv = st ? s1[ni] : s0[ni];
                floatx4 p;
#pragma unroll
                for (int j = 0; j < 4; ++j) p[j] = __builtin_amdgcn_exp2f(sv[j] - SHIFT2);
                if (st) lac1 += p; else lac0 += p;
#pragma unroll
                for (int j = 0; j < 4; ++j) {
                    int r = quad * 4 + j;
                    int chunk = ((ni * 16 + l16) >> 3) ^ ((r >> 1) & 7);
                    Ps[wave][st][r * 64 + chunk * 8 + (l16 & 7)] = (bf16_t)p[j];
                }
            }
        }

        bf16x8 pf[2][2];
#pragma unroll
        for (int st = 0; st < 2; ++st)
#pragma unroll
            for (int k2 = 0; k2 < 2; ++k2) {
                int chunk = (k2 * 4 + quad) ^ ((l16 >> 1) & 7);
                pf[st][k2] = *(const bf16x8*)&Ps[wave][st][l16 * 64 + chunk * 8];
            }

#pragma unroll
        for (int k2 = 0; k2 < 2; ++k2)
#pragma unroll
            for (int ni = 0; ni < 8; ++ni) {
                int r = ni * 16 + l16;
                int c = (k2 * 4 + quad) ^ (l16 & 7) ^ (((l16 >> 3) & 1) << 2);
                bf16x8 vf = *(const bf16x8*)&VTs[r * 64 + c * 8];
                o0[ni] = mfma_bf16(pf[0][k2], vf, o0[ni]);
                o1[ni] = mfma_bf16(pf[1][k2], vf, o1[ni]);
            }
        __syncthreads();
    }

#pragma unroll
    for (int off = 1; off < 16; off <<= 1) {
#pragma unroll
        for (int j = 0; j < 4; ++j) {
            lac0[j] += __shfl_xor(lac0[j], off);
            lac1[j] += __shfl_xor(lac1[j], off);
        }
    }

#pragma unroll
    for (int st = 0; st < 2; ++st) {
#pragma unroll
        for (int j = 0; j < 4; ++j) {
            float rl = 1.0f / (st ? lac1[j] : lac0[j]);
            int s_row = q0 + st * 16 + quad * 4 + j;
#pragma unroll
            for (int ni = 0; ni < 8; ++ni) {
                float v = (st ? o1[ni][j] : o0[ni][j]) * rl;
                int col = h * HD + ni * 16 + l16;
                ao[(long)s_row * DIM + col] = (bf16_t)v;
                if (s_row >= SIMG) out_txt[(long)(s_row - SIMG) * DIM + col] = v;
            }
        }
    }
}

// ---------------- launch ----------------
extern "C" void kernel_launch(void* const* d_in, const int* in_sizes, int n_in,
                              void* d_out, int out_size, void* d_ws, size_t ws_size,
                              hipStream_t stream) {
    const float* hid = (const float*)d_in[0];
    const float* enc = (const float*)d_in[1];
    const float* rope_cos = (const float*)d_in[2];
    const float* rope_sin = (const float*)d_in[3];
    const float* wq = (const float*)d_in[4];
    const float* bq = (const float*)d_in[5];
    const float* wk = (const float*)d_in[6];
    const float* bk = (const float*)d_in[7];
    const float* wv = (const float*)d_in[8];
    const float* bv = (const float*)d_in[9];
    const float* nqw = (const float*)d_in[10];
    const float* nkw = (const float*)d_in[11];
    const float* wo = (const float*)d_in[12];
    const float* bo = (const float*)d_in[13];
    float* out = (float*)d_out;

    char* ws = (char*)d_ws;
    bf16_t* xb   = (bf16_t*)(ws);                 // 2304*3072 bf16  = 14,155,776 B
    bf16_t* wTq  = (bf16_t*)(ws + 14155776L);     // 3*3072*3072 bf16
    bf16_t* woT  = (bf16_t*)(ws + 70778880L);     // 3072*3072 bf16
    bf16_t* qb   = (bf16_t*)(ws + 89653248L);     // 24*2304*128 bf16
    bf16_t* kbuf = (bf16_t*)(ws + 103809024L);
    bf16_t* vT   = (bf16_t*)(ws + 117964800L);
    bf16_t* ao   = (bf16_t*)(ws + 132120576L);    // 2304*3072 bf16

    k_convert_x<<<6912, 256, 0, stream>>>(hid, enc, xb);
    k_wT4<<<dim3(48, 48, 4), 256, 0, stream>>>(wq, wk, wv, wo, wTq, woT);
    k_gemm_qkv<<<dim3(72, 18), 256, 0, stream>>>(xb, wTq, bq, bk, bv, rope_cos, rope_sin,
                                                 nqw, nkw, qb, kbuf, vT);
    k_attn<<<dim3(18, 24), 256, 0, stream>>>(qb, kbuf, vT, ao, out + (long)SIMG * DIM);
    k_gemm_bt<<<dim3(24, 16), 256, 0, stream>>>(ao, woT, bo, (bf16_t*)nullptr, out, SIMG, DIM, DIM);
}